// Round 4
// baseline (73.887 us; speedup 1.0000x reference)
//
#include <hip/hip_runtime.h>
#include <math.h>

#define Bsz 8
#define Kc 4
#define Nn 16
#define Ss 64
#define Hh 512
#define F2 1024   // 2H = per-part K dim

__device__ __forceinline__ float logsigf(float x) {
    // log_sigmoid(x) = min(x,0) - log1p(exp(-|x|))  (matches jax.nn.log_sigmoid)
    return fminf(x, 0.0f) - log1pf(expf(-fabsf(x)));
}

// ---------------- K1: GEMM, in-block split-K, no partials ----------------
// grid (8,16,2): tile 64m x 32n.  z=0: T = seg @ W1[:1024]; z=1: V = vid @ W1[1024:].
// 512 threads = 8 waves; waves 0-3 (h=0) do K[0:512], waves 4-7 (h=1) K[512:1024].
// Per half: BK=32, 16 steps, double-buffered LDS, 4m x 2n microtile (8 out/thread).
// Epilogue: half-1 acc goes through LDS, half-0 adds and writes the final matrix.
__global__ __launch_bounds__(512) void gemm_kernel(
    const float* __restrict__ seg, const float* __restrict__ vid,
    const float* __restrict__ W1,
    float* __restrict__ Tfin, float* __restrict__ Vfin, int* __restrict__ tick)
{
    const int z = blockIdx.z;
    const float* __restrict__ Amat = z ? vid : seg;
    const float* __restrict__ Bmat = W1 + (z ? (size_t)F2 * Hh : 0);
    float* __restrict__ Out = z ? Vfin : Tfin;
    const int r0 = blockIdx.x * 64;
    const int n0 = blockIdx.y * 32;
    const int t = threadIdx.x;

    // zero the K2 tickets for this call (graph replays): one block does it
    if (blockIdx.x == 0 && blockIdx.y == 0 && z == 0 && t < Bsz) tick[t] = 0;

    const int h   = t >> 8;      // K-half
    const int tid = t & 255;

    __shared__ __align__(16) float As[2][2][32][68];  // [half][buf][k][m] transposed
    __shared__ __align__(16) float Bs[2][2][32][36];  // [half][buf][k][n] padded

    const int mt = (tid >> 4) << 2;   // 0..60
    const int nt = (tid & 15) << 1;   // 0..30
    const int ar  = tid >> 3;         // 0..31 (+32 for second)
    const int ak4 = (tid & 7) << 2;   // 0..28
    const int bk  = tid >> 3;         // 0..31
    const int bc4 = (tid & 7) << 2;   // 0..28

    float4 ra0, ra1, rb0;
    auto load_step = [&](int s) {
        const int k0 = h * 512 + s * 32;
        ra0 = *reinterpret_cast<const float4*>(Amat + (size_t)(r0 + ar) * F2 + k0 + ak4);
        ra1 = *reinterpret_cast<const float4*>(Amat + (size_t)(r0 + ar + 32) * F2 + k0 + ak4);
        rb0 = *reinterpret_cast<const float4*>(Bmat + (size_t)(k0 + bk) * Hh + n0 + bc4);
    };
    auto write_step = [&](int buf) {
        As[h][buf][ak4 + 0][ar] = ra0.x; As[h][buf][ak4 + 1][ar] = ra0.y;
        As[h][buf][ak4 + 2][ar] = ra0.z; As[h][buf][ak4 + 3][ar] = ra0.w;
        As[h][buf][ak4 + 0][ar + 32] = ra1.x; As[h][buf][ak4 + 1][ar + 32] = ra1.y;
        As[h][buf][ak4 + 2][ar + 32] = ra1.z; As[h][buf][ak4 + 3][ar + 32] = ra1.w;
        *reinterpret_cast<float4*>(&Bs[h][buf][bk][bc4]) = rb0;
    };

    float acc[4][2] = {{0.f}};
    load_step(0);
    write_step(0);
    __syncthreads();
    #pragma unroll 1
    for (int s = 0; s < 16; ++s) {
        const int cur = s & 1;
        if (s + 1 < 16) load_step(s + 1);
        #pragma unroll
        for (int kk = 0; kk < 32; ++kk) {
            float4 a4 = *reinterpret_cast<const float4*>(&As[h][cur][kk][mt]);
            float2 b2 = *reinterpret_cast<const float2*>(&Bs[h][cur][kk][nt]);
            float av[4] = {a4.x, a4.y, a4.z, a4.w};
            #pragma unroll
            for (int i = 0; i < 4; ++i) {
                acc[i][0] = fmaf(av[i], b2.x, acc[i][0]);
                acc[i][1] = fmaf(av[i], b2.y, acc[i][1]);
            }
        }
        if (s + 1 < 16) {
            write_step(cur ^ 1);
            __syncthreads();
        }
    }
    __syncthreads();                       // all compute done before LDS reuse
    float* red = &As[0][0][0][0];          // 2048 floats, reuse staging LDS
    if (h == 1) {
        #pragma unroll
        for (int i = 0; i < 4; ++i) {
            red[tid * 8 + i * 2 + 0] = acc[i][0];
            red[tid * 8 + i * 2 + 1] = acc[i][1];
        }
    }
    __syncthreads();
    if (h == 0) {
        #pragma unroll
        for (int i = 0; i < 4; ++i) {
            float2 o;
            o.x = acc[i][0] + red[tid * 8 + i * 2 + 0];
            o.y = acc[i][1] + red[tid * 8 + i * 2 + 1];
            *reinterpret_cast<float2*>(Out + (size_t)(r0 + mt + i) * Hh + n0 + nt) = o;
        }
    }
}

// ---------------- K2: combine + per-b ticket + DP + outputs ----------------
// 256 blocks = (b:8, sc:8 s-chunk, rq:4 kn-quarter), 256 threads.
// Each block: logits for 16 kn x 8 s.  Last block per b (atomic ticket) runs DP.
__global__ __launch_bounds__(256) void combine_dp_kernel(
    const float* __restrict__ Tfin, const float* __restrict__ Vfin,
    const float* __restrict__ b1, const float* __restrict__ w2,
    const float* __restrict__ b2, const float* __restrict__ labels,
    float* __restrict__ logits, int* __restrict__ tick, float* __restrict__ out)
{
    const int bid = blockIdx.x;        // b*32 + sc*4 + rq
    const int b  = bid >> 5;
    const int sc = (bid >> 2) & 7;
    const int rq = bid & 3;
    const int t = threadIdx.x;
    const int wave = t >> 6, lane = t & 63;
    __shared__ float Vs[8][520];
    __shared__ int lastFlag;
    {
        const int s_l = t & 7;
        const int h0  = (t >> 3) << 4;
        const float* row = Vfin + (size_t)(b * Ss + sc * 8 + s_l) * Hh + h0;
        #pragma unroll
        for (int x4 = 0; x4 < 4; ++x4)
            *reinterpret_cast<float4*>(&Vs[s_l][h0 + 4 * x4]) =
                *reinterpret_cast<const float4*>(row + 4 * x4);
    }
    float w2r[8], b1r[8];
    #pragma unroll
    for (int j = 0; j < 8; ++j) { w2r[j] = w2[lane + 64 * j]; b1r[j] = b1[lane + 64 * j]; }
    const float bias2 = b2[0];
    __syncthreads();
    #pragma unroll
    for (int i = 0; i < 4; ++i) {
        const int kn = rq * 16 + wave * 4 + i;
        const int r  = b * 64 + kn;
        const float* trow = Tfin + (size_t)r * Hh;
        float tj[8];
        #pragma unroll
        for (int j = 0; j < 8; ++j) tj[j] = trow[lane + 64 * j] + b1r[j];
        #pragma unroll
        for (int s = 0; s < 8; ++s) {
            float sum = 0.f;
            #pragma unroll
            for (int j = 0; j < 8; ++j)
                sum = fmaf(fmaxf(tj[j] + Vs[s][lane + 64 * j], 0.f), w2r[j], sum);
            #pragma unroll
            for (int off = 32; off > 0; off >>= 1) sum += __shfl_xor(sum, off);
            if (lane == 0) logits[(size_t)r * Ss + sc * 8 + s] = sum + bias2;
        }
    }
    // ---- ticket: last block of this b runs the DP ----
    __threadfence();                 // release: push logits to device scope
    __syncthreads();
    if (t == 0) lastFlag = (atomicAdd(&tick[b], 1) == 31) ? 1 : 0;
    __syncthreads();
    if (!lastFlag) return;
    __threadfence();                 // acquire: invalidate stale L2 lines

    // ---- DP for batch b: wave k handles (b,k); lane = s ----
    const int k = wave;
    const float* lg = logits + (size_t)((b * Kc + k) * Nn) * Ss;
    float lv[Nn], L[Nn];
    #pragma unroll
    for (int n = 0; n < Nn; ++n) {
        lv[n] = lg[n * Ss + lane];
        L[n] = logsigf(lv[n]);
    }
    float arr = -100.0f;
    unsigned long long msk[Nn];
    #pragma unroll
    for (int n = Nn - 1; n >= 0; --n) {
        float c = (n == Nn - 1) ? L[n] : (L[n] + arr);
        bool in_band = (lane >= n) && (lane <= (Ss - Nn) + n);
        float m = in_band ? c : -INFINITY;
        #pragma unroll
        for (int off = 1; off < 64; off <<= 1) {
            float o = __shfl(m, min(lane + off, 63));
            m = fmaxf(m, o);
        }
        float row = in_band ? fmaxf(m, -100.0f) : -100.0f;
        float rn = __shfl(row, min(lane + 1, 63));
        if (lane == 63) rn = -1e30f;
        msk[n] = __ballot(in_band && (c >= rn));
        arr = row;
    }
    const float best = __shfl(arr, 0);
    float agg = 0.f;
    int start = 0;
    int alignv[Nn];
    bool dead = false;
    #pragma unroll
    for (int n = 0; n < Nn; ++n) {
        unsigned long long m2 = dead ? 0ull : (msk[n] & (~0ull << start));
        if (m2) {
            const int s = __builtin_ctzll(m2);
            agg += __shfl(lv[n], s);
            alignv[n] = s;
            start = s + 1;
        } else {
            alignv[n] = 0;
            dead = true;   // reference walk: node never advances again
        }
    }
    __syncthreads();                 // Vs no longer needed; reuse LDS
    __shared__ float bestS[Kc], aggS[Kc];
    __shared__ int alS[Kc][Nn];
    if (lane == 0) {
        bestS[k] = best; aggS[k] = agg;
        #pragma unroll
        for (int n = 0; n < Nn; ++n) alS[k][n] = alignv[n];
    }
    __syncthreads();
    if (t == 0) {
        int kb = 0; float bb = bestS[0];
        #pragma unroll
        for (int kk = 1; kk < Kc; ++kk)
            if (bestS[kk] > bb) { bb = bestS[kk]; kb = kk; }
        out[b] = 1.0f / (1.0f + expf(-aggS[kb]));
        out[Bsz + b] = labels[b];
        #pragma unroll
        for (int n = 0; n < Nn; ++n)
            out[2 * Bsz + b * Nn + n] = (float)alS[kb][n];
    }
}

extern "C" void kernel_launch(void* const* d_in, const int* in_sizes, int n_in,
                              void* d_out, int out_size, void* d_ws, size_t ws_size,
                              hipStream_t stream) {
    const float* seg    = (const float*)d_in[0]; // (8,4,16,1024)
    const float* vid    = (const float*)d_in[1]; // (8,64,1024)
    const float* labels = (const float*)d_in[2]; // (8,)
    const float* W1     = (const float*)d_in[3]; // (2048,512)
    const float* b1     = (const float*)d_in[4]; // (512,)
    const float* w2     = (const float*)d_in[5]; // (512,)
    const float* b2     = (const float*)d_in[6]; // (1,)
    float* out = (float*)d_out;                  // 144 floats

    float* Tfin   = (float*)d_ws;                 // 512*512
    float* Vfin   = Tfin + (size_t)512 * Hh;      // 512*512
    float* logits = Vfin + (size_t)512 * Hh;      // 32768
    int*   tick   = (int*)(logits + 32768);       // 8 ints

    hipLaunchKernelGGL(gemm_kernel, dim3(8, 16, 2), dim3(512), 0, stream,
                       seg, vid, W1, Tfin, Vfin, tick);
    hipLaunchKernelGGL(combine_dp_kernel, dim3(256), dim3(256), 0, stream,
                       Tfin, Vfin, b1, w2, b2, labels, logits, tick, out);
}

// Round 5
// 54.361 us; speedup vs baseline: 1.3592x; 1.3592x over previous
//
#include <hip/hip_runtime.h>
#include <math.h>

#define Bsz 8
#define Kc 4
#define Nn 16
#define Ss 64
#define Hh 512
#define F2 1024   // 2H = per-part K dim

__device__ __forceinline__ float logsigf(float x) {
    // log_sigmoid(x) = min(x,0) - log1p(exp(-|x|))  (matches jax.nn.log_sigmoid)
    return fminf(x, 0.0f) - log1pf(expf(-fabsf(x)));
}

// ---------------- K1: GEMM, in-block split-K, no partials ----------------
// grid (8,16,2): tile 64m x 32n.  z=0: T = seg @ W1[:1024]; z=1: V = vid @ W1[1024:].
// 512 threads = 8 waves; waves 0-3 (h=0) do K[0:512], waves 4-7 (h=1) K[512:1024].
// Per half: BK=32, 16 steps, double-buffered LDS, 4m x 2n microtile.
// Epilogue: half-1 acc goes through LDS, half-0 adds and writes the final matrix.
__global__ __launch_bounds__(512) void gemm_kernel(
    const float* __restrict__ seg, const float* __restrict__ vid,
    const float* __restrict__ W1,
    float* __restrict__ Tfin, float* __restrict__ Vfin)
{
    const int z = blockIdx.z;
    const float* __restrict__ Amat = z ? vid : seg;
    const float* __restrict__ Bmat = W1 + (z ? (size_t)F2 * Hh : 0);
    float* __restrict__ Out = z ? Vfin : Tfin;
    const int r0 = blockIdx.x * 64;
    const int n0 = blockIdx.y * 32;
    const int t = threadIdx.x;
    const int h   = t >> 8;      // K-half
    const int tid = t & 255;

    __shared__ __align__(16) float As[2][2][32][68];  // [half][buf][k][m] transposed
    __shared__ __align__(16) float Bs[2][2][32][36];  // [half][buf][k][n] padded

    const int mt = (tid >> 4) << 2;   // 0..60
    const int nt = (tid & 15) << 1;   // 0..30
    const int ar  = tid >> 3;         // 0..31 (+32 for second)
    const int ak4 = (tid & 7) << 2;   // 0..28
    const int bk  = tid >> 3;         // 0..31
    const int bc4 = (tid & 7) << 2;   // 0..28

    float4 ra0, ra1, rb0;
    auto load_step = [&](int s) {
        const int k0 = h * 512 + s * 32;
        ra0 = *reinterpret_cast<const float4*>(Amat + (size_t)(r0 + ar) * F2 + k0 + ak4);
        ra1 = *reinterpret_cast<const float4*>(Amat + (size_t)(r0 + ar + 32) * F2 + k0 + ak4);
        rb0 = *reinterpret_cast<const float4*>(Bmat + (size_t)(k0 + bk) * Hh + n0 + bc4);
    };
    auto write_step = [&](int buf) {
        As[h][buf][ak4 + 0][ar] = ra0.x; As[h][buf][ak4 + 1][ar] = ra0.y;
        As[h][buf][ak4 + 2][ar] = ra0.z; As[h][buf][ak4 + 3][ar] = ra0.w;
        As[h][buf][ak4 + 0][ar + 32] = ra1.x; As[h][buf][ak4 + 1][ar + 32] = ra1.y;
        As[h][buf][ak4 + 2][ar + 32] = ra1.z; As[h][buf][ak4 + 3][ar + 32] = ra1.w;
        *reinterpret_cast<float4*>(&Bs[h][buf][bk][bc4]) = rb0;
    };

    float acc[4][2] = {{0.f}};
    load_step(0);
    write_step(0);
    __syncthreads();
    #pragma unroll 1
    for (int s = 0; s < 16; ++s) {
        const int cur = s & 1;
        if (s + 1 < 16) load_step(s + 1);
        #pragma unroll
        for (int kk = 0; kk < 32; ++kk) {
            float4 a4 = *reinterpret_cast<const float4*>(&As[h][cur][kk][mt]);
            float2 b2 = *reinterpret_cast<const float2*>(&Bs[h][cur][kk][nt]);
            float av[4] = {a4.x, a4.y, a4.z, a4.w};
            #pragma unroll
            for (int i = 0; i < 4; ++i) {
                acc[i][0] = fmaf(av[i], b2.x, acc[i][0]);
                acc[i][1] = fmaf(av[i], b2.y, acc[i][1]);
            }
        }
        if (s + 1 < 16) {
            write_step(cur ^ 1);
            __syncthreads();
        }
    }
    __syncthreads();                       // all compute done before LDS reuse
    float* red = &As[0][0][0][0];          // 2048 floats, reuse staging LDS
    if (h == 1) {
        #pragma unroll
        for (int i = 0; i < 4; ++i) {
            red[tid * 8 + i * 2 + 0] = acc[i][0];
            red[tid * 8 + i * 2 + 1] = acc[i][1];
        }
    }
    __syncthreads();
    if (h == 0) {
        #pragma unroll
        for (int i = 0; i < 4; ++i) {
            float2 o;
            o.x = acc[i][0] + red[tid * 8 + i * 2 + 0];
            o.y = acc[i][1] + red[tid * 8 + i * 2 + 1];
            *reinterpret_cast<float2*>(Out + (size_t)(r0 + mt + i) * Hh + n0 + nt) = o;
        }
    }
}

// ---------------- K2: combine: logits = w2 . relu(T + V + b1) + b2 ----------------
// 256 blocks = (b:8, sc:8 s-chunk, rq:4 kn-quarter), 256 threads.
__global__ __launch_bounds__(256) void combine_kernel(
    const float* __restrict__ Tfin, const float* __restrict__ Vfin,
    const float* __restrict__ b1, const float* __restrict__ w2,
    const float* __restrict__ b2, float* __restrict__ logits)
{
    const int bid = blockIdx.x;        // b*32 + sc*4 + rq
    const int b  = bid >> 5;
    const int sc = (bid >> 2) & 7;
    const int rq = bid & 3;
    const int t = threadIdx.x;
    const int wave = t >> 6, lane = t & 63;
    __shared__ float Vs[8][520];
    {
        const int s_l = t & 7;
        const int h0  = (t >> 3) << 4;
        const float* row = Vfin + (size_t)(b * Ss + sc * 8 + s_l) * Hh + h0;
        #pragma unroll
        for (int x4 = 0; x4 < 4; ++x4)
            *reinterpret_cast<float4*>(&Vs[s_l][h0 + 4 * x4]) =
                *reinterpret_cast<const float4*>(row + 4 * x4);
    }
    float w2r[8], b1r[8];
    #pragma unroll
    for (int j = 0; j < 8; ++j) { w2r[j] = w2[lane + 64 * j]; b1r[j] = b1[lane + 64 * j]; }
    const float bias2 = b2[0];
    __syncthreads();
    #pragma unroll
    for (int i = 0; i < 4; ++i) {
        const int kn = rq * 16 + wave * 4 + i;
        const int r  = b * 64 + kn;
        const float* trow = Tfin + (size_t)r * Hh;
        float tj[8];
        #pragma unroll
        for (int j = 0; j < 8; ++j) tj[j] = trow[lane + 64 * j] + b1r[j];
        #pragma unroll
        for (int s = 0; s < 8; ++s) {
            float sum = 0.f;
            #pragma unroll
            for (int j = 0; j < 8; ++j)
                sum = fmaf(fmaxf(tj[j] + Vs[s][lane + 64 * j], 0.f), w2r[j], sum);
            #pragma unroll
            for (int off = 32; off > 0; off >>= 1) sum += __shfl_xor(sum, off);
            if (lane == 0) logits[(size_t)r * Ss + sc * 8 + s] = sum + bias2;
        }
    }
}

// ---------------- K3: DP + register traceback + argmax + outputs ----------------
// One block per b; wave k handles (b,k); lane = s.
__global__ __launch_bounds__(256) void dp_kernel(
    const float* __restrict__ logits, const float* __restrict__ labels,
    float* __restrict__ out)
{
    const int b = blockIdx.x;
    const int t = threadIdx.x;
    const int k = t >> 6, lane = t & 63;
    const float* lg = logits + (size_t)((b * Kc + k) * Nn) * Ss;
    float lv[Nn], L[Nn];
    #pragma unroll
    for (int n = 0; n < Nn; ++n) {
        lv[n] = lg[n * Ss + lane];
        L[n] = logsigf(lv[n]);
    }
    float arr = -100.0f;
    unsigned long long msk[Nn];
    #pragma unroll
    for (int n = Nn - 1; n >= 0; --n) {
        float c = (n == Nn - 1) ? L[n] : (L[n] + arr);
        bool in_band = (lane >= n) && (lane <= (Ss - Nn) + n);
        float m = in_band ? c : -INFINITY;
        #pragma unroll
        for (int off = 1; off < 64; off <<= 1) {
            float o = __shfl(m, min(lane + off, 63));
            m = fmaxf(m, o);
        }
        float row = in_band ? fmaxf(m, -100.0f) : -100.0f;
        float rn = __shfl(row, min(lane + 1, 63));
        if (lane == 63) rn = -1e30f;
        msk[n] = __ballot(in_band && (c >= rn));
        arr = row;
    }
    const float best = __shfl(arr, 0);
    float agg = 0.f;
    int start = 0;
    int alignv[Nn];
    bool dead = false;
    #pragma unroll
    for (int n = 0; n < Nn; ++n) {
        unsigned long long m2 = dead ? 0ull : (msk[n] & (~0ull << start));
        if (m2) {
            const int s = __builtin_ctzll(m2);
            agg += __shfl(lv[n], s);
            alignv[n] = s;
            start = s + 1;
        } else {
            alignv[n] = 0;
            dead = true;   // reference walk: node never advances again
        }
    }
    __shared__ float bestS[Kc], aggS[Kc];
    __shared__ int alS[Kc][Nn];
    if (lane == 0) {
        bestS[k] = best; aggS[k] = agg;
        #pragma unroll
        for (int n = 0; n < Nn; ++n) alS[k][n] = alignv[n];
    }
    __syncthreads();
    if (t == 0) {
        int kb = 0; float bb = bestS[0];
        #pragma unroll
        for (int kk = 1; kk < Kc; ++kk)
            if (bestS[kk] > bb) { bb = bestS[kk]; kb = kk; }
        out[b] = 1.0f / (1.0f + expf(-aggS[kb]));
        out[Bsz + b] = labels[b];
        #pragma unroll
        for (int n = 0; n < Nn; ++n)
            out[2 * Bsz + b * Nn + n] = (float)alS[kb][n];
    }
}

extern "C" void kernel_launch(void* const* d_in, const int* in_sizes, int n_in,
                              void* d_out, int out_size, void* d_ws, size_t ws_size,
                              hipStream_t stream) {
    const float* seg    = (const float*)d_in[0]; // (8,4,16,1024)
    const float* vid    = (const float*)d_in[1]; // (8,64,1024)
    const float* labels = (const float*)d_in[2]; // (8,)
    const float* W1     = (const float*)d_in[3]; // (2048,512)
    const float* b1     = (const float*)d_in[4]; // (512,)
    const float* w2     = (const float*)d_in[5]; // (512,)
    const float* b2     = (const float*)d_in[6]; // (1,)
    float* out = (float*)d_out;                  // 144 floats

    float* Tfin   = (float*)d_ws;                 // 512*512
    float* Vfin   = Tfin + (size_t)512 * Hh;      // 512*512
    float* logits = Vfin + (size_t)512 * Hh;      // 32768

    hipLaunchKernelGGL(gemm_kernel, dim3(8, 16, 2), dim3(512), 0, stream,
                       seg, vid, W1, Tfin, Vfin);
    hipLaunchKernelGGL(combine_kernel, dim3(256), dim3(256), 0, stream,
                       Tfin, Vfin, b1, w2, b2, logits);
    hipLaunchKernelGGL(dp_kernel, dim3(Bsz), dim3(256), 0, stream, logits, labels, out);
}

// Round 6
// 49.231 us; speedup vs baseline: 1.5008x; 1.1042x over previous
//
#include <hip/hip_runtime.h>
#include <math.h>

#define Bsz 8
#define Kc 4
#define Nn 16
#define Ss 64
#define Hh 512
#define F2 1024   // 2H = per-part K dim

__device__ __forceinline__ float logsigf(float x) {
    // log_sigmoid(x) = min(x,0) - log1p(exp(-|x|))  (matches jax.nn.log_sigmoid)
    return fminf(x, 0.0f) - log1pf(expf(-fabsf(x)));
}

// ---- DPP wave64 inclusive scans (VALU-speed; replaces ds_bpermute shfl chains) ----
// ctrl: 0x111=row_shr:1, 0x112=row_shr:2, 0x114=row_shr:4, 0x118=row_shr:8,
//       0x142=row_bcast15 (lanes16-31<-15, 48-63<-47), 0x143=row_bcast31 (32-63<-31)
template<int Ctrl, int RowMask>
__device__ __forceinline__ float dpp_add(float x) {
    int v = __builtin_amdgcn_update_dpp(0, __float_as_int(x), Ctrl, RowMask, 0xf, false);
    return x + __int_as_float(v);
}
template<int Ctrl, int RowMask>
__device__ __forceinline__ float dpp_max(float x) {
    int v = __builtin_amdgcn_update_dpp(__float_as_int(-INFINITY), __float_as_int(x),
                                        Ctrl, RowMask, 0xf, false);
    return fmaxf(x, __int_as_float(v));
}
__device__ __forceinline__ float wave_scan_add(float x) {   // lane63 = wave sum
    x = dpp_add<0x111, 0xf>(x);
    x = dpp_add<0x112, 0xf>(x);
    x = dpp_add<0x114, 0xf>(x);
    x = dpp_add<0x118, 0xf>(x);
    x = dpp_add<0x142, 0xa>(x);
    x = dpp_add<0x143, 0xc>(x);
    return x;
}
__device__ __forceinline__ float wave_scan_max(float x) {   // inclusive prefix max
    x = dpp_max<0x111, 0xf>(x);
    x = dpp_max<0x112, 0xf>(x);
    x = dpp_max<0x114, 0xf>(x);
    x = dpp_max<0x118, 0xf>(x);
    x = dpp_max<0x142, 0xa>(x);
    x = dpp_max<0x143, 0xc>(x);
    return x;
}

// ---------------- K1: GEMM, in-block split-K, no partials ----------------
// grid (8,16,2): tile 64m x 32n.  z=0: T = seg @ W1[:1024]; z=1: V = vid @ W1[1024:].
// 512 threads = 8 waves; waves 0-3 (h=0) do K[0:512], waves 4-7 (h=1) K[512:1024].
__global__ __launch_bounds__(512) void gemm_kernel(
    const float* __restrict__ seg, const float* __restrict__ vid,
    const float* __restrict__ W1,
    float* __restrict__ Tfin, float* __restrict__ Vfin)
{
    const int z = blockIdx.z;
    const float* __restrict__ Amat = z ? vid : seg;
    const float* __restrict__ Bmat = W1 + (z ? (size_t)F2 * Hh : 0);
    float* __restrict__ Out = z ? Vfin : Tfin;
    const int r0 = blockIdx.x * 64;
    const int n0 = blockIdx.y * 32;
    const int t = threadIdx.x;
    const int h   = t >> 8;      // K-half
    const int tid = t & 255;

    __shared__ __align__(16) float As[2][2][32][68];  // [half][buf][k][m] transposed
    __shared__ __align__(16) float Bs[2][2][32][36];  // [half][buf][k][n] padded

    const int mt = (tid >> 4) << 2;
    const int nt = (tid & 15) << 1;
    const int ar  = tid >> 3;
    const int ak4 = (tid & 7) << 2;
    const int bk  = tid >> 3;
    const int bc4 = (tid & 7) << 2;

    float4 ra0, ra1, rb0;
    auto load_step = [&](int s) {
        const int k0 = h * 512 + s * 32;
        ra0 = *reinterpret_cast<const float4*>(Amat + (size_t)(r0 + ar) * F2 + k0 + ak4);
        ra1 = *reinterpret_cast<const float4*>(Amat + (size_t)(r0 + ar + 32) * F2 + k0 + ak4);
        rb0 = *reinterpret_cast<const float4*>(Bmat + (size_t)(k0 + bk) * Hh + n0 + bc4);
    };
    auto write_step = [&](int buf) {
        As[h][buf][ak4 + 0][ar] = ra0.x; As[h][buf][ak4 + 1][ar] = ra0.y;
        As[h][buf][ak4 + 2][ar] = ra0.z; As[h][buf][ak4 + 3][ar] = ra0.w;
        As[h][buf][ak4 + 0][ar + 32] = ra1.x; As[h][buf][ak4 + 1][ar + 32] = ra1.y;
        As[h][buf][ak4 + 2][ar + 32] = ra1.z; As[h][buf][ak4 + 3][ar + 32] = ra1.w;
        *reinterpret_cast<float4*>(&Bs[h][buf][bk][bc4]) = rb0;
    };

    float acc[4][2] = {{0.f}};
    load_step(0);
    write_step(0);
    __syncthreads();
    #pragma unroll 1
    for (int s = 0; s < 16; ++s) {
        const int cur = s & 1;
        if (s + 1 < 16) load_step(s + 1);
        #pragma unroll
        for (int kk = 0; kk < 32; ++kk) {
            float4 a4 = *reinterpret_cast<const float4*>(&As[h][cur][kk][mt]);
            float2 b2 = *reinterpret_cast<const float2*>(&Bs[h][cur][kk][nt]);
            float av[4] = {a4.x, a4.y, a4.z, a4.w};
            #pragma unroll
            for (int i = 0; i < 4; ++i) {
                acc[i][0] = fmaf(av[i], b2.x, acc[i][0]);
                acc[i][1] = fmaf(av[i], b2.y, acc[i][1]);
            }
        }
        if (s + 1 < 16) {
            write_step(cur ^ 1);
            __syncthreads();
        }
    }
    __syncthreads();
    float* red = &As[0][0][0][0];
    if (h == 1) {
        #pragma unroll
        for (int i = 0; i < 4; ++i) {
            red[tid * 8 + i * 2 + 0] = acc[i][0];
            red[tid * 8 + i * 2 + 1] = acc[i][1];
        }
    }
    __syncthreads();
    if (h == 0) {
        #pragma unroll
        for (int i = 0; i < 4; ++i) {
            float2 o;
            o.x = acc[i][0] + red[tid * 8 + i * 2 + 0];
            o.y = acc[i][1] + red[tid * 8 + i * 2 + 1];
            *reinterpret_cast<float2*>(Out + (size_t)(r0 + mt + i) * Hh + n0 + nt) = o;
        }
    }
}

// ---------------- K2: combine (DPP reduce): logits = w2 . relu(T+V+b1) + b2 ----
__global__ __launch_bounds__(256) void combine_kernel(
    const float* __restrict__ Tfin, const float* __restrict__ Vfin,
    const float* __restrict__ b1, const float* __restrict__ w2,
    const float* __restrict__ b2, float* __restrict__ logits)
{
    const int bid = blockIdx.x;        // b*32 + sc*4 + rq
    const int b  = bid >> 5;
    const int sc = (bid >> 2) & 7;
    const int rq = bid & 3;
    const int t = threadIdx.x;
    const int wave = t >> 6, lane = t & 63;
    __shared__ float Vs[8][520];
    {
        const int s_l = t & 7;
        const int h0  = (t >> 3) << 4;
        const float* row = Vfin + (size_t)(b * Ss + sc * 8 + s_l) * Hh + h0;
        #pragma unroll
        for (int x4 = 0; x4 < 4; ++x4)
            *reinterpret_cast<float4*>(&Vs[s_l][h0 + 4 * x4]) =
                *reinterpret_cast<const float4*>(row + 4 * x4);
    }
    float w2r[8], b1r[8];
    #pragma unroll
    for (int j = 0; j < 8; ++j) { w2r[j] = w2[lane + 64 * j]; b1r[j] = b1[lane + 64 * j]; }
    const float bias2 = b2[0];
    __syncthreads();
    #pragma unroll
    for (int i = 0; i < 4; ++i) {
        const int kn = rq * 16 + wave * 4 + i;
        const int r  = b * 64 + kn;
        const float* trow = Tfin + (size_t)r * Hh;
        float tj[8];
        #pragma unroll
        for (int j = 0; j < 8; ++j) tj[j] = trow[lane + 64 * j] + b1r[j];
        #pragma unroll
        for (int s = 0; s < 8; ++s) {
            float sum = 0.f;
            #pragma unroll
            for (int j = 0; j < 8; ++j)
                sum = fmaf(fmaxf(tj[j] + Vs[s][lane + 64 * j], 0.f), w2r[j], sum);
            sum = wave_scan_add(sum);          // lane 63 = full dot
            if (lane == 63) logits[(size_t)r * Ss + sc * 8 + s] = sum + bias2;
        }
    }
}

// ---------------- K3: DP via DPP prefix-max (reversed lanes) + traceback ----
// One block per b; wave k handles (b,k).  Lane rl holds s = 63 - rl so the
// suffix-cummax over s is an inclusive PREFIX max over rl (6 DPP steps).
__global__ __launch_bounds__(256) void dp_kernel(
    const float* __restrict__ logits, const float* __restrict__ labels,
    float* __restrict__ out)
{
    const int b = blockIdx.x;
    const int t = threadIdx.x;
    const int k = t >> 6, rl = t & 63;
    const int sI = 63 - rl;
    __shared__ float lgs[Kc][Nn][Ss];
    __shared__ unsigned long long ch[Kc][Nn];
    __shared__ float bestS[Kc], aggS[Kc];
    __shared__ int alS[Kc][Nn];
    const float* lg = logits + (size_t)((b * Kc + k) * Nn) * Ss;
    float lv[Nn];
    #pragma unroll
    for (int n = 0; n < Nn; ++n) {
        lv[n] = lg[n * Ss + sI];
        lgs[k][n][sI] = lv[n];
    }
    float arr = -100.0f;
    #pragma unroll
    for (int n = Nn - 1; n >= 0; --n) {
        const float L = logsigf(lv[n]);
        const float c = (n == Nn - 1) ? L : (L + arr);
        const bool in_band = (rl <= 63 - n) && (rl >= 15 - n);   // s in [n, 48+n]
        float m = in_band ? c : -INFINITY;
        m = wave_scan_max(m);                      // prefix over rl = suffix over s
        const float row = in_band ? fmaxf(m, -100.0f) : -100.0f;
        // rn = row[s+1] = row at lane rl-1; boundary lanes 16/32/48 patched via bcast
        float rnA = __int_as_float(__builtin_amdgcn_update_dpp(
            __float_as_int(-1e30f), __float_as_int(row), 0x111, 0xf, 0xf, false));
        float b15 = __int_as_float(__builtin_amdgcn_update_dpp(
            0, __float_as_int(row), 0x142, 0xa, 0xf, false));
        float b31 = __int_as_float(__builtin_amdgcn_update_dpp(
            0, __float_as_int(row), 0x143, 0xc, 0xf, false));
        float rn = ((rl & 15) == 0 && rl != 0) ? ((rl == 32) ? b31 : b15) : rnA;
        unsigned long long mask = __ballot(in_band && (c >= rn));
        if (rl == 0) ch[k][n] = __brevll(mask);    // bit s (natural order)
        arr = row;
    }
    const float best = __shfl(arr, 63);            // row_{n=0}[s=0]
    __syncthreads();                               // lgs, ch visible
    if (rl == 0) {
        float agg = 0.f;
        int start = 0;
        bool dead = false;
        int alignv[Nn];
        #pragma unroll
        for (int n = 0; n < Nn; ++n) {
            unsigned long long m2 = dead ? 0ull : (ch[k][n] & (~0ull << start));
            if (m2) {
                const int s = __builtin_ctzll(m2);
                agg += lgs[k][n][s];
                alignv[n] = s;
                start = s + 1;
            } else {
                alignv[n] = 0;
                dead = true;   // reference walk: node never advances again
            }
        }
        bestS[k] = best; aggS[k] = agg;
        #pragma unroll
        for (int n = 0; n < Nn; ++n) alS[k][n] = alignv[n];
    }
    __syncthreads();
    if (t == 0) {
        int kb = 0; float bb = bestS[0];
        #pragma unroll
        for (int kk = 1; kk < Kc; ++kk)
            if (bestS[kk] > bb) { bb = bestS[kk]; kb = kk; }
        out[b] = 1.0f / (1.0f + expf(-aggS[kb]));
        out[Bsz + b] = labels[b];
        #pragma unroll
        for (int n = 0; n < Nn; ++n)
            out[2 * Bsz + b * Nn + n] = (float)alS[kb][n];
    }
}

extern "C" void kernel_launch(void* const* d_in, const int* in_sizes, int n_in,
                              void* d_out, int out_size, void* d_ws, size_t ws_size,
                              hipStream_t stream) {
    const float* seg    = (const float*)d_in[0]; // (8,4,16,1024)
    const float* vid    = (const float*)d_in[1]; // (8,64,1024)
    const float* labels = (const float*)d_in[2]; // (8,)
    const float* W1     = (const float*)d_in[3]; // (2048,512)
    const float* b1     = (const float*)d_in[4]; // (512,)
    const float* w2     = (const float*)d_in[5]; // (512,)
    const float* b2     = (const float*)d_in[6]; // (1,)
    float* out = (float*)d_out;                  // 144 floats

    float* Tfin   = (float*)d_ws;                 // 512*512
    float* Vfin   = Tfin + (size_t)512 * Hh;      // 512*512
    float* logits = Vfin + (size_t)512 * Hh;      // 32768

    hipLaunchKernelGGL(gemm_kernel, dim3(8, 16, 2), dim3(512), 0, stream,
                       seg, vid, W1, Tfin, Vfin);
    hipLaunchKernelGGL(combine_kernel, dim3(256), dim3(256), 0, stream,
                       Tfin, Vfin, b1, w2, b2, logits);
    hipLaunchKernelGGL(dp_kernel, dim3(Bsz), dim3(256), 0, stream, logits, labels, out);
}